// Round 8
// baseline (578.333 us; speedup 1.0000x reference)
//
#include <hip/hip_runtime.h>

#define MR 50176        // B_*N = 1024*49 rows
#define DIMC 512
#define NWIN 49
#define NBATCH 1024
#define NHEADS 16
#define ATTN_SCALE 0.17677669529663689f  // 32^-0.5

typedef short bf16x8 __attribute__((ext_vector_type(8)));
typedef float f32x4 __attribute__((ext_vector_type(4)));
typedef unsigned int u32;

__device__ __forceinline__ unsigned short f2bf(float f) {
  union { float f; u32 u; } v; v.f = f;
  u32 u = v.u;
  u += 0x7FFFu + ((u >> 16) & 1u);   // round-to-nearest-even
  return (unsigned short)(u >> 16);
}
__device__ __forceinline__ float bits_f(u32 u) {
  union { u32 u; float f; } v; v.u = u; return v.f;
}

// HW packed f32->bf16 (RNE, identical to f2bf for normal values): 1 VALU op
// replaces 2x f2bf (8 ops) + merge. The single biggest VALU cut in the
// CONVA staging pack (160 -> 16 ops per K-tile per wave).
__device__ __forceinline__ u32 cvtpk(float lo, float hi) {
  u32 r;
  asm("v_cvt_pk_bf16_f32 %0, %1, %2" : "=v"(r) : "v"(lo), "v"(hi));
  return r;
}

// Packed-swizzled bf16 layout (16B chunks, XOR by row&7).
__device__ __forceinline__ size_t pk_chunk(int r, int c) {
  return (((size_t)(r >> 3) * 8 + (c >> 3)) * 64 +
          ((r & 7) * 8 + ((c & 7) ^ (r & 7)))) << 4;
}

typedef const __attribute__((address_space(1))) u32* gp_t;
typedef __attribute__((address_space(3))) u32* lp_t;
__device__ __forceinline__ void glds16(const void* g, void* l) {
  __builtin_amdgcn_global_load_lds((gp_t)g, (lp_t)l, 16, 0, 0);
}

// Inline-asm global load: compiler emits NO waitcnt for it — manual counted
// vmcnt waits are the only synchronization (keeps the glds16 pipeline alive).
__device__ __forceinline__ f32x4 gload4(const float* p) {
  f32x4 r;
  asm volatile("global_load_dwordx4 %0, %1, off" : "=v"(r) : "v"(p));
  return r;
}

// ---------------------------------------------------------------------------
// 5 weight slices -> one packed bf16 [2560][512] (k,q,v,g,proj transposed).
// ---------------------------------------------------------------------------
__global__ __launch_bounds__(256) void prep_w_pack(
    const float* __restrict__ Wqkv, const float* __restrict__ Wqkv2,
    const float* __restrict__ Wgw, const float* __restrict__ Wproj,
    short* __restrict__ Wp) {
  const int tid = blockIdx.x * 256 + threadIdx.x;   // 163840 total
  const int li = tid & 63, gl = tid >> 6;
  const int kline = gl & 7, group = gl >> 3;
  const int rr = li >> 3, pp = li & 7;
  const int row = group * 8 + rr;                    // 0..2559
  const int k = kline * 64 + ((pp ^ rr) << 3);
  const int n = row & 511, mat = row >> 9;
  const float* W; int ldw, col;
  if (mat == 0)      { W = Wqkv;  ldw = 1536; col = 512 + n; }
  else if (mat == 1) { W = Wqkv2; ldw = 1536; col = n; }
  else if (mat == 2) { W = Wqkv2; ldw = 1536; col = 1024 + n; }
  else if (mat == 3) { W = Wgw;   ldw = 512;  col = n; }
  else               { W = Wproj; ldw = 512;  col = n; }
  float h[8];
#pragma unroll
  for (int j = 0; j < 8; ++j) h[j] = W[(size_t)(k + j) * ldw + col];
  u32 w0 = cvtpk(h[0], h[1]);
  u32 w1 = cvtpk(h[2], h[3]);
  u32 w2 = cvtpk(h[4], h[5]);
  u32 w3 = cvtpk(h[6], h[7]);
  ((uint4*)Wp)[tid] = make_uint4(w0, w1, w2, w3);
}

// ---------------------------------------------------------------------------
// Multi-output GEMM, 128x128 tile, double-buffered LDS (2 x 16KB per operand,
// 64KB total), ONE barrier per K-tile, counted vmcnt (never 0 mid-loop).
// koff splits the row-tile space across launches (y = xcd + 8*(koff + k)) so
// big dispatches can be halved for profiler visibility without breaking the
// per-launch XCD swizzle.
//
// CONVA steady state, iteration kt (slot s = kt&1):
//   1. issue B(kt+1) glds -> Bs[s^1]         queue: A(kt+1)8, B(kt+1)4
//   2. vmcnt(4)  (drain A(kt+1) regs only) + sched_barrier(0)
//   3. cvt_pk pack -> ds_write As[s^1]
//   4. issue A(kt+2) asm loads               queue: B(kt+1)4, A(kt+2)8
//   5. compute kt from As[s], Bs[s]          (B-DMA + A-loads overlap MFMA)
//   6. vmcnt(8) lgkm(0)  (drain B(kt+1); A(kt+2) stays in flight)
//   7. s_barrier
// Tails: kt==6 -> vmcnt(0); kt==7 -> compute only.
// ---------------------------------------------------------------------------
struct GemmCfg {
  const short* A[4];
  const float* Af[4];
  const float* bias[4];
  short* out[4];
  int wrow0[4];
};

template <int LNX, bool OUT_F32, bool CONVA>
__global__ __launch_bounds__(256) void gemm_glds(
    GemmCfg cfg, const short* __restrict__ Wp, float* __restrict__ outf,
    int koff) {
  __shared__ short As[2][8192];   // 2 slots x 16 KB (128 rows x 64 K bf16)
  __shared__ short Bs[2][8192];   // 2 slots x 16 KB

  const int t = threadIdx.x, w = t >> 6, lane = t & 63;
  const int l15 = lane & 15, q = lane >> 4;
  const int wm = w >> 1, wn = w & 1;
  const int id = blockIdx.x;
  const int xcd = id & 7, slot = id >> 3;
  const int bx = slot & ((1 << LNX) - 1);
  const int y = xcd + ((koff + (slot >> LNX)) << 3);
  const int row0 = y * 128;
  const int unit = bx >> 2, sub = bx & 3;
  const float* bias = cfg.bias[unit];
  short* outb = cfg.out[unit];
  const int nw0 = cfg.wrow0[unit] + sub * 128;
  const int col0 = sub * 128;

  f32x4 acc[4][4];
#pragma unroll
  for (int i = 0; i < 4; ++i)
#pragma unroll
    for (int j = 0; j < 4; ++j) acc[i][j] = {0.f, 0.f, 0.f, 0.f};

  const size_t lb = (size_t)lane * 16;
  const int r7 = l15 & 7, hi8 = l15 >> 3;

#define COMPUTE_TILE(SL)                                                      \
  do {                                                                        \
    _Pragma("unroll")                                                         \
    for (int sk = 0; sk < 2; ++sk) {                                          \
      const int sw = ((sk * 4 + q) ^ r7);                                     \
      const int pos = (r7 * 8 + sw) * 8;                                      \
      bf16x8 af[4], bfr[4];                                                   \
      _Pragma("unroll")                                                       \
      for (int i = 0; i < 4; ++i)                                             \
        af[i] = *(const bf16x8*)&As[SL][((wm * 8 + i * 2 + hi8) << 9) + pos]; \
      _Pragma("unroll")                                                       \
      for (int j = 0; j < 4; ++j)                                             \
        bfr[j] = *(const bf16x8*)&Bs[SL][((wn * 8 + j * 2 + hi8) << 9) + pos];\
      _Pragma("unroll")                                                       \
      for (int i = 0; i < 4; ++i)                                             \
        _Pragma("unroll")                                                     \
        for (int j = 0; j < 4; ++j)                                           \
          acc[i][j] = __builtin_amdgcn_mfma_f32_16x16x32_bf16(                \
              af[i], bfr[j], acc[i][j], 0, 0, 0);                             \
    }                                                                         \
  } while (0)

  if constexpr (CONVA) {
    const int rr = lane >> 3, pp = lane & 7;
    const float* abase =
        cfg.Af[unit] + (size_t)(row0 + w * 32 + rr) * DIMC + ((pp ^ rr) << 3);
    f32x4 ar[4][2];

    auto loadA = [&](int kt2) {
#pragma unroll
      for (int jj = 0; jj < 4; ++jj) {
        const float* s = abase + (size_t)jj * 8 * DIMC + kt2 * 64;
        ar[jj][0] = gload4(s);
        ar[jj][1] = gload4(s + 4);
      }
    };
    auto stageB = [&](int kt2) {
      const int sl = kt2 & 1;
#pragma unroll
      for (int jj = 0; jj < 4; ++jj) {
        const int rg = w * 4 + jj;
        const char* gb =
            (const char*)Wp + ((((size_t)(nw0 >> 3) + rg) * 8 + kt2) << 10);
        glds16(gb + lb, &Bs[sl][(size_t)rg << 9]);
      }
    };
    auto packA = [&](int sl) {
#pragma unroll
      for (int jj = 0; jj < 4; ++jj) {
        u32 w0 = cvtpk(ar[jj][0][0], ar[jj][0][1]);
        u32 w1 = cvtpk(ar[jj][0][2], ar[jj][0][3]);
        u32 w2 = cvtpk(ar[jj][1][0], ar[jj][1][1]);
        u32 w3 = cvtpk(ar[jj][1][2], ar[jj][1][3]);
        *(uint4*)&As[sl][(((size_t)(w * 4 + jj)) << 9) + (size_t)lane * 8] =
            make_uint4(w0, w1, w2, w3);
      }
    };

    // ---- prologue: stage tile 0, start A(1) ----
    loadA(0);                                   // queue: A0(8)
    __builtin_amdgcn_sched_barrier(0);          // pin issue order A0 < B0
    stageB(0);                                  // queue: A0(8), B0(4)
    asm volatile("s_waitcnt vmcnt(4)" ::: "memory");   // drain A0
    __builtin_amdgcn_sched_barrier(0);
    packA(0);
    loadA(1);                                   // queue: B0(4), A1(8)
    asm volatile("s_waitcnt vmcnt(8) lgkmcnt(0)" ::: "memory");  // drain B0
    asm volatile("s_barrier" ::: "memory");

    for (int kt = 0; kt < 8; ++kt) {
      const int s = kt & 1;
      if (kt < 7) {
        stageB(kt + 1);                         // queue: A(kt+1)8, B(kt+1)4
        asm volatile("s_waitcnt vmcnt(4)" ::: "memory");  // drain A(kt+1)
        __builtin_amdgcn_sched_barrier(0);
        packA(s ^ 1);
        if (kt < 6) loadA(kt + 2);              // queue: B(kt+1)4, A(kt+2)8
      }
      COMPUTE_TILE(s);
      if (kt < 6)
        asm volatile("s_waitcnt vmcnt(8) lgkmcnt(0)" ::: "memory");
      else if (kt == 6)
        asm volatile("s_waitcnt vmcnt(0) lgkmcnt(0)" ::: "memory");
      if (kt < 7) asm volatile("s_barrier" ::: "memory");
    }
  } else {
    const short* Ap = cfg.A[unit];
    auto stageAB = [&](int kt2) {
      const int sl = kt2 & 1;
#pragma unroll
      for (int jj = 0; jj < 4; ++jj) {
        const int rg = w * 4 + jj;
        const char* ga =
            (const char*)Ap + ((((size_t)(row0 >> 3) + rg) * 8 + kt2) << 10);
        glds16(ga + lb, &As[sl][(size_t)rg << 9]);
        const char* gb =
            (const char*)Wp + ((((size_t)(nw0 >> 3) + rg) * 8 + kt2) << 10);
        glds16(gb + lb, &Bs[sl][(size_t)rg << 9]);
      }
    };
    stageAB(0);
    asm volatile("s_waitcnt vmcnt(0)" ::: "memory");
    asm volatile("s_barrier" ::: "memory");
    for (int kt = 0; kt < 8; ++kt) {
      const int s = kt & 1;
      if (kt < 7) stageAB(kt + 1);      // DMA overlaps compute below
      COMPUTE_TILE(s);
      if (kt < 7) {
        asm volatile("s_waitcnt vmcnt(0) lgkmcnt(0)" ::: "memory");
        asm volatile("s_barrier" ::: "memory");
      }
    }
  }
#undef COMPUTE_TILE

#pragma unroll
  for (int j = 0; j < 4; ++j) {
    const int C = col0 + wn * 64 + j * 16 + l15;
    const float bv = bias[C];
#pragma unroll
    for (int i = 0; i < 4; ++i) {
      const int R = row0 + wm * 64 + i * 16 + q * 4;
      if constexpr (OUT_F32) {
#pragma unroll
        for (int r = 0; r < 4; ++r)
          outf[(size_t)(R + r) * DIMC + C] = acc[i][j][r] + bv;
      } else {
        const u32 p01 = cvtpk(acc[i][j][0] + bv, acc[i][j][1] + bv);
        const u32 p23 = cvtpk(acc[i][j][2] + bv, acc[i][j][3] + bv);
        char* base0 = (char*)outb + ((C & 7) << 1);
        *(short*)(base0 + pk_chunk(R + 0, C >> 3)) = (short)p01;
        *(short*)(base0 + pk_chunk(R + 1, C >> 3)) = (short)(p01 >> 16);
        *(short*)(base0 + pk_chunk(R + 2, C >> 3)) = (short)p23;
        *(short*)(base0 + pk_chunk(R + 3, C >> 3)) = (short)(p23 >> 16);
      }
    }
  }
}

// ---------------------------------------------------------------------------
// MFMA attention, one window per wave (packed I/O; cvt_pk conversions).
// ---------------------------------------------------------------------------
__global__ __launch_bounds__(256) void attn_mfma(
    const short* __restrict__ kbuf, const short* __restrict__ qbuf,
    const short* __restrict__ vbuf, const short* __restrict__ gbuf,
    const float* __restrict__ a_scalar, short* __restrict__ obuf) {
  __shared__ short pls[4][64 * 40];
  __shared__ short vls[4][32 * 72];

  const int t = threadIdx.x;
  const int w = t >> 6, lane = t & 63;
  const int l15 = lane & 15, q = lane >> 4;
  const int wid = blockIdx.x * 4 + w;
  const int b = wid >> 4, h = wid & 15;
  const int row0 = b * NWIN;
  const float aval = a_scalar[0];
  short* P = pls[w];
  short* VT = vls[w];

#pragma unroll
  for (int it = 0; it < 5; ++it) {
    int off = (it * 64 + lane) * 8;
    if (off < 32 * 72) *(uint4*)&VT[off] = make_uint4(0u, 0u, 0u, 0u);
  }

  bf16x8 kf[4];
#pragma unroll
  for (int mj = 0; mj < 4; ++mj) {
    int m = mj * 16 + l15; if (m > 48) m = 48;
    kf[mj] = *(const bf16x8*)((const char*)kbuf + pk_chunk(row0 + m, h * 4 + q));
  }
  bf16x8 qf[4];
#pragma unroll
  for (int mi = 0; mi < 4; ++mi) {
    int n = mi * 16 + l15; if (n > 48) n = 48;
    const size_t off = pk_chunk(row0 + n, h * 4 + q);
    uint4 qa = *(const uint4*)((const char*)qbuf + off);
    uint4 ga = *(const uint4*)((const char*)gbuf + off);
    u32* qa_ = (u32*)&qa;
    u32* ga_ = (u32*)&ga;
    uint4 res; u32* r_ = (u32*)&res;
#pragma unroll
    for (int jj = 0; jj < 4; ++jj) {
      float lo = bits_f(qa_[jj] << 16) * bits_f(ga_[jj] << 16);
      float hi = bits_f(qa_[jj] & 0xffff0000u) * bits_f(ga_[jj] & 0xffff0000u);
      r_[jj] = cvtpk(lo, hi);
    }
    qf[mi] = *(bf16x8*)&res;
  }
#pragma unroll
  for (int it = 0; it < 4; ++it) {
    int chunk = it * 64 + lane;
    if (chunk < 196) {
      int n = chunk >> 2, dcq = chunk & 3;
      uint4 v = *(const uint4*)((const char*)vbuf + pk_chunk(row0 + n, h * 4 + dcq));
      const short* vs = (const short*)&v;
#pragma unroll
      for (int j = 0; j < 8; ++j) VT[(dcq * 8 + j) * 72 + n] = vs[j];
    }
  }

  f32x4 s[4][4];
#pragma unroll
  for (int mi = 0; mi < 4; ++mi)
#pragma unroll
    for (int nj = 0; nj < 4; ++nj) {
      f32x4 z = {0.f, 0.f, 0.f, 0.f};
      s[mi][nj] = __builtin_amdgcn_mfma_f32_16x16x32_bf16(qf[mi], kf[nj], z, 0, 0, 0);
    }

#pragma unroll
  for (int mi = 0; mi < 4; ++mi)
#pragma unroll
    for (int nj = 0; nj < 4; ++nj) {
      const bool valid = (nj * 16 + l15) < NWIN;
#pragma unroll
      for (int r = 0; r < 4; ++r)
        s[mi][nj][r] = valid ? __expf(ATTN_SCALE * s[mi][nj][r]) : 0.f;
    }

  float lsum[4][4];
#pragma unroll
  for (int mi = 0; mi < 4; ++mi)
#pragma unroll
    for (int r = 0; r < 4; ++r) {
      float part = s[mi][0][r] + s[mi][1][r] + s[mi][2][r] + s[mi][3][r];
      part += __shfl_xor(part, 1, 64);
      part += __shfl_xor(part, 2, 64);
      part += __shfl_xor(part, 4, 64);
      part += __shfl_xor(part, 8, 64);
      lsum[mi][r] = part;
    }

  f32x4 o[4][2];
#pragma unroll
  for (int mi = 0; mi < 4; ++mi)
#pragma unroll
    for (int dj = 0; dj < 2; ++dj) o[mi][dj] = {0.f, 0.f, 0.f, 0.f};

#pragma unroll
  for (int c = 0; c < 2; ++c) {
#pragma unroll
    for (int mi = 0; mi < 4; ++mi)
#pragma unroll
      for (int r = 0; r < 4; ++r) {
        const int n = mi * 16 + q * 4 + r;
        const int m0 = (c * 2 + 0) * 16 + l15;
        const int m1 = (c * 2 + 1) * 16 + l15;
        float v0 = s[mi][c * 2 + 0][r];
        float v1 = s[mi][c * 2 + 1][r];
        if (m0 == n) v0 += aval * lsum[mi][r];
        if (m1 == n) v1 += aval * lsum[mi][r];
        const u32 p = cvtpk(v0, v1);
        P[n * 40 + l15] = (short)p;
        P[n * 40 + 16 + l15] = (short)(p >> 16);
      }
    bf16x8 bfr[2];
#pragma unroll
    for (int dj = 0; dj < 2; ++dj)
      bfr[dj] = *(const bf16x8*)&VT[(dj * 16 + l15) * 72 + c * 32 + q * 8];
#pragma unroll
    for (int mi = 0; mi < 4; ++mi) {
      bf16x8 af = *(const bf16x8*)&P[(mi * 16 + l15) * 40 + q * 8];
#pragma unroll
      for (int dj = 0; dj < 2; ++dj)
        o[mi][dj] = __builtin_amdgcn_mfma_f32_16x16x32_bf16(af, bfr[dj],
                                                            o[mi][dj], 0, 0, 0);
    }
  }

#pragma unroll
  for (int mi = 0; mi < 4; ++mi)
#pragma unroll
    for (int r = 0; r < 4; ++r) {
      const int n = mi * 16 + q * 4 + r;
      if (n < NWIN) {
        const float rl = 1.0f / lsum[mi][r];
        const u32 p = cvtpk(o[mi][0][r] * rl, o[mi][1][r] * rl);
        char* base = (char*)obuf + ((l15 & 7) << 1);
        *(short*)(base + pk_chunk(row0 + n, h * 4 + (l15 >> 3))) = (short)p;
        *(short*)(base + pk_chunk(row0 + n, h * 4 + 2 + (l15 >> 3))) =
            (short)(p >> 16);
      }
    }
}

// ---------------------------------------------------------------------------
extern "C" void kernel_launch(void* const* d_in, const int* in_sizes, int n_in,
                              void* d_out, int out_size, void* d_ws,
                              size_t ws_size, hipStream_t stream) {
  const float* x     = (const float*)d_in[0];
  const float* x2    = (const float*)d_in[1];
  const float* x3    = (const float*)d_in[2];
  const float* Wqkv  = (const float*)d_in[3];
  const float* bqkv  = (const float*)d_in[4];
  const float* Wqkv2 = (const float*)d_in[5];
  const float* bqkv2 = (const float*)d_in[6];
  const float* Wgw   = (const float*)d_in[7];
  const float* bgw   = (const float*)d_in[8];
  const float* Wproj = (const float*)d_in[9];
  const float* bproj = (const float*)d_in[10];
  const float* a     = (const float*)d_in[11];

  char* ws = (char*)d_ws;
  const size_t WTSZ = (size_t)2560 * DIMC * sizeof(short);   // 2.62 MB
  const size_t BSZ  = (size_t)MR * DIMC * sizeof(short);     // 51.4 MB
  short* wt_all = (short*)ws;

  short* kbuf = (short*)(ws + WTSZ);
  short* qbuf = (short*)(ws + WTSZ + BSZ);
  short* vbuf = (short*)(ws + WTSZ + 2 * BSZ);
  short* gbuf = (short*)(ws + WTSZ + 3 * BSZ);
  short* obuf = (short*)(ws + WTSZ + 4 * BSZ);   // 259.7 MB total

  prep_w_pack<<<640, 256, 0, stream>>>(Wqkv, Wqkv2, Wgw, Wproj, wt_all);

  // Stage 1: fused fp32->bf16 conversion inside the GEMM.
  // Split into two half-dispatches (k-groups 0..23 and 24..48) so each is
  // ~110 us — anything slower (i.e. attn, per the time accounting) then
  // surfaces in the rocprof top-5 with counters. XCD swizzle intact per launch.
  GemmCfg s1 = {};
  s1.Af[0] = x;  s1.Af[1] = x3; s1.Af[2] = x3; s1.Af[3] = x2;
  s1.bias[0] = bqkv + 512; s1.bias[1] = bqkv2;
  s1.bias[2] = bqkv2 + 1024; s1.bias[3] = bgw;
  s1.out[0] = kbuf; s1.out[1] = qbuf; s1.out[2] = vbuf; s1.out[3] = gbuf;
  s1.wrow0[0] = 0; s1.wrow0[1] = 512; s1.wrow0[2] = 1024; s1.wrow0[3] = 1536;
  gemm_glds<4, false, true><<<16 * 8 * 24, 256, 0, stream>>>(s1, wt_all,
                                                             nullptr, 0);
  gemm_glds<4, false, true><<<16 * 8 * 25, 256, 0, stream>>>(s1, wt_all,
                                                             nullptr, 24);

  attn_mfma<<<(NBATCH * NHEADS) / 4, 256, 0, stream>>>(kbuf, qbuf, vbuf,
                                                       gbuf, a, obuf);

  GemmCfg pj = {};
  pj.A[0] = obuf; pj.bias[0] = bproj; pj.out[0] = nullptr; pj.wrow0[0] = 2048;
  gemm_glds<2, true, false><<<4 * 392, 256, 0, stream>>>(pj, wt_all,
                                                         (float*)d_out, 0);
}

// Round 9
// 565.436 us; speedup vs baseline: 1.0228x; 1.0228x over previous
//
#include <hip/hip_runtime.h>

#define MR 50176        // B_*N = 1024*49 rows
#define DIMC 512
#define NWIN 49
#define NBATCH 1024
#define NHEADS 16
#define ATTN_SCALE 0.17677669529663689f  // 32^-0.5

typedef short bf16x8 __attribute__((ext_vector_type(8)));
typedef float f32x4 __attribute__((ext_vector_type(4)));
typedef unsigned int u32;

__device__ __forceinline__ float bits_f(u32 u) {
  union { u32 u; float f; } v; v.u = u; return v.f;
}

// HW packed f32->bf16 (RNE): 1 VALU op per 2 elements.
__device__ __forceinline__ u32 cvtpk(float lo, float hi) {
  u32 r;
  asm("v_cvt_pk_bf16_f32 %0, %1, %2" : "=v"(r) : "v"(lo), "v"(hi));
  return r;
}

// Packed-swizzled bf16 layout (16B chunks, XOR by row&7).
__device__ __forceinline__ size_t pk_chunk(int r, int c) {
  return (((size_t)(r >> 3) * 8 + (c >> 3)) * 64 +
          ((r & 7) * 8 + ((c & 7) ^ (r & 7)))) << 4;
}

typedef const __attribute__((address_space(1))) u32* gp_t;
typedef __attribute__((address_space(3))) u32* lp_t;
__device__ __forceinline__ void glds16(const void* g, void* l) {
  __builtin_amdgcn_global_load_lds((gp_t)g, (lp_t)l, 16, 0, 0);
}

// Inline-asm global load: compiler emits NO waitcnt for it — manual counted
// vmcnt waits are the only synchronization (keeps the glds16 pipeline alive).
__device__ __forceinline__ f32x4 gload4(const float* p) {
  f32x4 r;
  asm volatile("global_load_dwordx4 %0, %1, off" : "=v"(r) : "v"(p));
  return r;
}

// ---------------------------------------------------------------------------
// 5 weight slices -> one packed bf16 [2560][512] (k,q,v,g,proj transposed).
// ---------------------------------------------------------------------------
__global__ __launch_bounds__(256) void prep_w_pack(
    const float* __restrict__ Wqkv, const float* __restrict__ Wqkv2,
    const float* __restrict__ Wgw, const float* __restrict__ Wproj,
    short* __restrict__ Wp) {
  const int tid = blockIdx.x * 256 + threadIdx.x;   // 163840 total
  const int li = tid & 63, gl = tid >> 6;
  const int kline = gl & 7, group = gl >> 3;
  const int rr = li >> 3, pp = li & 7;
  const int row = group * 8 + rr;                    // 0..2559
  const int k = kline * 64 + ((pp ^ rr) << 3);
  const int n = row & 511, mat = row >> 9;
  const float* W; int ldw, col;
  if (mat == 0)      { W = Wqkv;  ldw = 1536; col = 512 + n; }
  else if (mat == 1) { W = Wqkv2; ldw = 1536; col = n; }
  else if (mat == 2) { W = Wqkv2; ldw = 1536; col = 1024 + n; }
  else if (mat == 3) { W = Wgw;   ldw = 512;  col = n; }
  else               { W = Wproj; ldw = 512;  col = n; }
  float h[8];
#pragma unroll
  for (int j = 0; j < 8; ++j) h[j] = W[(size_t)(k + j) * ldw + col];
  ((uint4*)Wp)[tid] = make_uint4(cvtpk(h[0], h[1]), cvtpk(h[2], h[3]),
                                 cvtpk(h[4], h[5]), cvtpk(h[6], h[7]));
}

// ---------------------------------------------------------------------------
// Multi-output GEMM, 128x128 tile, 512 threads = 8 waves (64x32 per wave),
// double-buffered LDS (2 x 16KB per operand, 64KB total) -> 2 blocks/CU =
// 16 waves/CU (4/SIMD): 2x the wave concurrency of the 256-thread version,
// which R8 counters showed was the limit (all pipes <22% busy, stall-bound).
//
// CONVA steady state, iteration kt (slot s = kt&1):
//   1. issue B(kt+1) glds x2 -> Bs[s^1]      queue: A(kt+1)4, B(kt+1)2
//   2. vmcnt(2) (drain A regs) + sched_barrier(0)
//   3. cvt_pk pack -> ds_write As[s^1]
//   4. issue A(kt+2) x4                      queue: B(kt+1)2, A(kt+2)4
//   5. compute kt                            (B-DMA + A-loads overlap MFMA)
//   6. vmcnt(4) lgkm(0) (drain B(kt+1); A(kt+2) in flight)
//   7. s_barrier
// Tails: kt==6 -> vmcnt(0); kt==7 -> compute only.
// ---------------------------------------------------------------------------
struct GemmCfg {
  const short* A[4];
  const float* Af[4];
  const float* bias[4];
  short* out[4];
  int wrow0[4];
};

template <int LNX, bool OUT_F32, bool CONVA>
__global__ __launch_bounds__(512, 4) void gemm_glds(
    GemmCfg cfg, const short* __restrict__ Wp, float* __restrict__ outf,
    int koff) {
  __shared__ short As[2][8192];   // 2 slots x 16 KB (128 rows x 64 K bf16)
  __shared__ short Bs[2][8192];   // 2 slots x 16 KB

  const int t = threadIdx.x, w = t >> 6, lane = t & 63;
  const int l15 = lane & 15, q = lane >> 4;
  const int wm = w >> 2, wn = w & 3;            // 2 x 4 wave grid, 64x32 each
  const int id = blockIdx.x;
  const int xcd = id & 7, slot = id >> 3;
  const int bx = slot & ((1 << LNX) - 1);
  const int y = xcd + ((koff + (slot >> LNX)) << 3);
  const int row0 = y * 128;
  const int unit = bx >> 2, sub = bx & 3;
  const float* bias = cfg.bias[unit];
  short* outb = cfg.out[unit];
  const int nw0 = cfg.wrow0[unit] + sub * 128;
  const int col0 = sub * 128;

  f32x4 acc[4][2];
#pragma unroll
  for (int i = 0; i < 4; ++i)
#pragma unroll
    for (int j = 0; j < 2; ++j) acc[i][j] = {0.f, 0.f, 0.f, 0.f};

  const size_t lb = (size_t)lane * 16;
  const int r7 = l15 & 7, hi8 = l15 >> 3;

#define COMPUTE_TILE(SL)                                                      \
  do {                                                                        \
    _Pragma("unroll")                                                         \
    for (int sk = 0; sk < 2; ++sk) {                                          \
      const int sw = ((sk * 4 + q) ^ r7);                                     \
      const int pos = (r7 * 8 + sw) * 8;                                      \
      bf16x8 af[4], bfr[2];                                                   \
      _Pragma("unroll")                                                       \
      for (int i = 0; i < 4; ++i)                                             \
        af[i] = *(const bf16x8*)&As[SL][((wm * 8 + i * 2 + hi8) << 9) + pos]; \
      _Pragma("unroll")                                                       \
      for (int j = 0; j < 2; ++j)                                             \
        bfr[j] = *(const bf16x8*)&Bs[SL][((wn * 4 + j * 2 + hi8) << 9) + pos];\
      _Pragma("unroll")                                                       \
      for (int i = 0; i < 4; ++i)                                             \
        _Pragma("unroll")                                                     \
        for (int j = 0; j < 2; ++j)                                           \
          acc[i][j] = __builtin_amdgcn_mfma_f32_16x16x32_bf16(                \
              af[i], bfr[j], acc[i][j], 0, 0, 0);                             \
    }                                                                         \
  } while (0)

  if constexpr (CONVA) {
    const int rr = lane >> 3, pp = lane & 7;
    // thread covers rows w*16 + rr + {0,8}; 8 waves x 16 rows = 128 rows
    const float* abase =
        cfg.Af[unit] + (size_t)(row0 + w * 16 + rr) * DIMC + ((pp ^ rr) << 3);
    f32x4 ar[2][2];

    auto loadA = [&](int kt2) {
#pragma unroll
      for (int jj = 0; jj < 2; ++jj) {
        const float* s = abase + (size_t)jj * 8 * DIMC + kt2 * 64;
        ar[jj][0] = gload4(s);
        ar[jj][1] = gload4(s + 4);
      }
    };
    auto stageB = [&](int kt2) {
      const int sl = kt2 & 1;
#pragma unroll
      for (int jj = 0; jj < 2; ++jj) {
        const int rg = w * 2 + jj;
        const char* gb =
            (const char*)Wp + ((((size_t)(nw0 >> 3) + rg) * 8 + kt2) << 10);
        glds16(gb + lb, &Bs[sl][(size_t)rg << 9]);
      }
    };
    auto packA = [&](int sl) {
#pragma unroll
      for (int jj = 0; jj < 2; ++jj) {
        *(uint4*)&As[sl][(((size_t)(w * 2 + jj)) << 9) + (size_t)lane * 8] =
            make_uint4(cvtpk(ar[jj][0][0], ar[jj][0][1]),
                       cvtpk(ar[jj][0][2], ar[jj][0][3]),
                       cvtpk(ar[jj][1][0], ar[jj][1][1]),
                       cvtpk(ar[jj][1][2], ar[jj][1][3]));
      }
    };

    // ---- prologue: stage tile 0, start A(1) ----
    loadA(0);                                   // queue: A0(4)
    __builtin_amdgcn_sched_barrier(0);          // pin issue order A0 < B0
    stageB(0);                                  // queue: A0(4), B0(2)
    asm volatile("s_waitcnt vmcnt(2)" ::: "memory");   // drain A0
    __builtin_amdgcn_sched_barrier(0);
    packA(0);
    loadA(1);                                   // queue: B0(2), A1(4)
    asm volatile("s_waitcnt vmcnt(4) lgkmcnt(0)" ::: "memory");  // drain B0
    asm volatile("s_barrier" ::: "memory");

    for (int kt = 0; kt < 8; ++kt) {
      const int s = kt & 1;
      if (kt < 7) {
        stageB(kt + 1);                         // queue: A(kt+1)4, B(kt+1)2
        asm volatile("s_waitcnt vmcnt(2)" ::: "memory");  // drain A(kt+1)
        __builtin_amdgcn_sched_barrier(0);
        packA(s ^ 1);
        if (kt < 6) loadA(kt + 2);              // queue: B(kt+1)2, A(kt+2)4
      }
      COMPUTE_TILE(s);
      if (kt < 6)
        asm volatile("s_waitcnt vmcnt(4) lgkmcnt(0)" ::: "memory");
      else if (kt == 6)
        asm volatile("s_waitcnt vmcnt(0) lgkmcnt(0)" ::: "memory");
      if (kt < 7) asm volatile("s_barrier" ::: "memory");
    }
  } else {
    const short* Ap = cfg.A[unit];
    auto stageAB = [&](int kt2) {
      const int sl = kt2 & 1;
#pragma unroll
      for (int jj = 0; jj < 2; ++jj) {
        const int rg = w * 2 + jj;
        const char* ga =
            (const char*)Ap + ((((size_t)(row0 >> 3) + rg) * 8 + kt2) << 10);
        glds16(ga + lb, &As[sl][(size_t)rg << 9]);
        const char* gb =
            (const char*)Wp + ((((size_t)(nw0 >> 3) + rg) * 8 + kt2) << 10);
        glds16(gb + lb, &Bs[sl][(size_t)rg << 9]);
      }
    };
    stageAB(0);
    asm volatile("s_waitcnt vmcnt(0)" ::: "memory");
    asm volatile("s_barrier" ::: "memory");
    for (int kt = 0; kt < 8; ++kt) {
      const int s = kt & 1;
      if (kt < 7) stageAB(kt + 1);      // DMA overlaps compute below
      COMPUTE_TILE(s);
      if (kt < 7) {
        asm volatile("s_waitcnt vmcnt(0) lgkmcnt(0)" ::: "memory");
        asm volatile("s_barrier" ::: "memory");
      }
    }
  }
#undef COMPUTE_TILE

#pragma unroll
  for (int j = 0; j < 2; ++j) {
    const int C = col0 + wn * 32 + j * 16 + l15;
    const float bv = bias[C];
#pragma unroll
    for (int i = 0; i < 4; ++i) {
      const int R = row0 + wm * 64 + i * 16 + q * 4;
      if constexpr (OUT_F32) {
#pragma unroll
        for (int r = 0; r < 4; ++r)
          outf[(size_t)(R + r) * DIMC + C] = acc[i][j][r] + bv;
      } else {
        const u32 p01 = cvtpk(acc[i][j][0] + bv, acc[i][j][1] + bv);
        const u32 p23 = cvtpk(acc[i][j][2] + bv, acc[i][j][3] + bv);
        char* base0 = (char*)outb + ((C & 7) << 1);
        *(short*)(base0 + pk_chunk(R + 0, C >> 3)) = (short)p01;
        *(short*)(base0 + pk_chunk(R + 1, C >> 3)) = (short)(p01 >> 16);
        *(short*)(base0 + pk_chunk(R + 2, C >> 3)) = (short)p23;
        *(short*)(base0 + pk_chunk(R + 3, C >> 3)) = (short)(p23 >> 16);
      }
    }
  }
}

// ---------------------------------------------------------------------------
// MFMA attention, one window per wave (packed I/O; cvt_pk conversions).
// ---------------------------------------------------------------------------
__global__ __launch_bounds__(256) void attn_mfma(
    const short* __restrict__ kbuf, const short* __restrict__ qbuf,
    const short* __restrict__ vbuf, const short* __restrict__ gbuf,
    const float* __restrict__ a_scalar, short* __restrict__ obuf) {
  __shared__ short pls[4][64 * 40];
  __shared__ short vls[4][32 * 72];

  const int t = threadIdx.x;
  const int w = t >> 6, lane = t & 63;
  const int l15 = lane & 15, q = lane >> 4;
  const int wid = blockIdx.x * 4 + w;
  const int b = wid >> 4, h = wid & 15;
  const int row0 = b * NWIN;
  const float aval = a_scalar[0];
  short* P = pls[w];
  short* VT = vls[w];

#pragma unroll
  for (int it = 0; it < 5; ++it) {
    int off = (it * 64 + lane) * 8;
    if (off < 32 * 72) *(uint4*)&VT[off] = make_uint4(0u, 0u, 0u, 0u);
  }

  bf16x8 kf[4];
#pragma unroll
  for (int mj = 0; mj < 4; ++mj) {
    int m = mj * 16 + l15; if (m > 48) m = 48;
    kf[mj] = *(const bf16x8*)((const char*)kbuf + pk_chunk(row0 + m, h * 4 + q));
  }
  bf16x8 qf[4];
#pragma unroll
  for (int mi = 0; mi < 4; ++mi) {
    int n = mi * 16 + l15; if (n > 48) n = 48;
    const size_t off = pk_chunk(row0 + n, h * 4 + q);
    uint4 qa = *(const uint4*)((const char*)qbuf + off);
    uint4 ga = *(const uint4*)((const char*)gbuf + off);
    u32* qa_ = (u32*)&qa;
    u32* ga_ = (u32*)&ga;
    uint4 res; u32* r_ = (u32*)&res;
#pragma unroll
    for (int jj = 0; jj < 4; ++jj) {
      float lo = bits_f(qa_[jj] << 16) * bits_f(ga_[jj] << 16);
      float hi = bits_f(qa_[jj] & 0xffff0000u) * bits_f(ga_[jj] & 0xffff0000u);
      r_[jj] = cvtpk(lo, hi);
    }
    qf[mi] = *(bf16x8*)&res;
  }
#pragma unroll
  for (int it = 0; it < 4; ++it) {
    int chunk = it * 64 + lane;
    if (chunk < 196) {
      int n = chunk >> 2, dcq = chunk & 3;
      uint4 v = *(const uint4*)((const char*)vbuf + pk_chunk(row0 + n, h * 4 + dcq));
      const short* vs = (const short*)&v;
#pragma unroll
      for (int j = 0; j < 8; ++j) VT[(dcq * 8 + j) * 72 + n] = vs[j];
    }
  }

  f32x4 s[4][4];
#pragma unroll
  for (int mi = 0; mi < 4; ++mi)
#pragma unroll
    for (int nj = 0; nj < 4; ++nj) {
      f32x4 z = {0.f, 0.f, 0.f, 0.f};
      s[mi][nj] = __builtin_amdgcn_mfma_f32_16x16x32_bf16(qf[mi], kf[nj], z, 0, 0, 0);
    }

#pragma unroll
  for (int mi = 0; mi < 4; ++mi)
#pragma unroll
    for (int nj = 0; nj < 4; ++nj) {
      const bool valid = (nj * 16 + l15) < NWIN;
#pragma unroll
      for (int r = 0; r < 4; ++r)
        s[mi][nj][r] = valid ? __expf(ATTN_SCALE * s[mi][nj][r]) : 0.f;
    }

  float lsum[4][4];
#pragma unroll
  for (int mi = 0; mi < 4; ++mi)
#pragma unroll
    for (int r = 0; r < 4; ++r) {
      float part = s[mi][0][r] + s[mi][1][r] + s[mi][2][r] + s[mi][3][r];
      part += __shfl_xor(part, 1, 64);
      part += __shfl_xor(part, 2, 64);
      part += __shfl_xor(part, 4, 64);
      part += __shfl_xor(part, 8, 64);
      lsum[mi][r] = part;
    }

  f32x4 o[4][2];
#pragma unroll
  for (int mi = 0; mi < 4; ++mi)
#pragma unroll
    for (int dj = 0; dj < 2; ++dj) o[mi][dj] = {0.f, 0.f, 0.f, 0.f};

#pragma unroll
  for (int c = 0; c < 2; ++c) {
#pragma unroll
    for (int mi = 0; mi < 4; ++mi)
#pragma unroll
      for (int r = 0; r < 4; ++r) {
        const int n = mi * 16 + q * 4 + r;
        const int m0 = (c * 2 + 0) * 16 + l15;
        const int m1 = (c * 2 + 1) * 16 + l15;
        float v0 = s[mi][c * 2 + 0][r];
        float v1 = s[mi][c * 2 + 1][r];
        if (m0 == n) v0 += aval * lsum[mi][r];
        if (m1 == n) v1 += aval * lsum[mi][r];
        const u32 p = cvtpk(v0, v1);
        P[n * 40 + l15] = (short)p;
        P[n * 40 + 16 + l15] = (short)(p >> 16);
      }
    bf16x8 bfr[2];
#pragma unroll
    for (int dj = 0; dj < 2; ++dj)
      bfr[dj] = *(const bf16x8*)&VT[(dj * 16 + l15) * 72 + c * 32 + q * 8];
#pragma unroll
    for (int mi = 0; mi < 4; ++mi) {
      bf16x8 af = *(const bf16x8*)&P[(mi * 16 + l15) * 40 + q * 8];
#pragma unroll
      for (int dj = 0; dj < 2; ++dj)
        o[mi][dj] = __builtin_amdgcn_mfma_f32_16x16x32_bf16(af, bfr[dj],
                                                            o[mi][dj], 0, 0, 0);
    }
  }

#pragma unroll
  for (int mi = 0; mi < 4; ++mi)
#pragma unroll
    for (int r = 0; r < 4; ++r) {
      const int n = mi * 16 + q * 4 + r;
      if (n < NWIN) {
        const float rl = 1.0f / lsum[mi][r];
        const u32 p = cvtpk(o[mi][0][r] * rl, o[mi][1][r] * rl);
        char* base = (char*)obuf + ((l15 & 7) << 1);
        *(short*)(base + pk_chunk(row0 + n, h * 4 + (l15 >> 3))) = (short)p;
        *(short*)(base + pk_chunk(row0 + n, h * 4 + 2 + (l15 >> 3))) =
            (short)(p >> 16);
      }
    }
}

// ---------------------------------------------------------------------------
extern "C" void kernel_launch(void* const* d_in, const int* in_sizes, int n_in,
                              void* d_out, int out_size, void* d_ws,
                              size_t ws_size, hipStream_t stream) {
  const float* x     = (const float*)d_in[0];
  const float* x2    = (const float*)d_in[1];
  const float* x3    = (const float*)d_in[2];
  const float* Wqkv  = (const float*)d_in[3];
  const float* bqkv  = (const float*)d_in[4];
  const float* Wqkv2 = (const float*)d_in[5];
  const float* bqkv2 = (const float*)d_in[6];
  const float* Wgw   = (const float*)d_in[7];
  const float* bgw   = (const float*)d_in[8];
  const float* Wproj = (const float*)d_in[9];
  const float* bproj = (const float*)d_in[10];
  const float* a     = (const float*)d_in[11];

  char* ws = (char*)d_ws;
  const size_t WTSZ = (size_t)2560 * DIMC * sizeof(short);   // 2.62 MB
  const size_t BSZ  = (size_t)MR * DIMC * sizeof(short);     // 51.4 MB
  short* wt_all = (short*)ws;

  short* kbuf = (short*)(ws + WTSZ);
  short* qbuf = (short*)(ws + WTSZ + BSZ);
  short* vbuf = (short*)(ws + WTSZ + 2 * BSZ);
  short* gbuf = (short*)(ws + WTSZ + 3 * BSZ);
  short* obuf = (short*)(ws + WTSZ + 4 * BSZ);   // 259.7 MB total

  prep_w_pack<<<640, 256, 0, stream>>>(Wqkv, Wqkv2, Wgw, Wproj, wt_all);

  // Stage 1: fused fp32->bf16 conversion inside the GEMM (single launch;
  // the R8 split cost ~30us and served its diagnostic purpose).
  GemmCfg s1 = {};
  s1.Af[0] = x;  s1.Af[1] = x3; s1.Af[2] = x3; s1.Af[3] = x2;
  s1.bias[0] = bqkv + 512; s1.bias[1] = bqkv2;
  s1.bias[2] = bqkv2 + 1024; s1.bias[3] = bgw;
  s1.out[0] = kbuf; s1.out[1] = qbuf; s1.out[2] = vbuf; s1.out[3] = gbuf;
  s1.wrow0[0] = 0; s1.wrow0[1] = 512; s1.wrow0[2] = 1024; s1.wrow0[3] = 1536;
  gemm_glds<4, false, true><<<16 * 392, 512, 0, stream>>>(s1, wt_all,
                                                          nullptr, 0);

  attn_mfma<<<(NBATCH * NHEADS) / 4, 256, 0, stream>>>(kbuf, qbuf, vbuf,
                                                       gbuf, a, obuf);

  GemmCfg pj = {};
  pj.A[0] = obuf; pj.bias[0] = bproj; pj.out[0] = nullptr; pj.wrow0[0] = 2048;
  gemm_glds<2, true, false><<<4 * 392, 512, 0, stream>>>(pj, wt_all,
                                                         (float*)d_out, 0);
}